// Round 14
// baseline (542.037 us; speedup 1.0000x reference)
//
#include <hip/hip_runtime.h>
#include <math.h>

#define NN 50000
#define NE 800000
#define IND 256
#define HD 64

// ---------------------------------------------------------------------------
// Fused node kernel. Block = 256 threads = 4 waves, covers 64 nodes.
// Wave q computes output columns [16q, 16q+16) -> weight rows are wave-uniform
// (scalar loads). Phase 1: h = tanh(x @ pw + pbias), written to global + LDS.
// Phase 2: Pa = h @ w1[0:64,:], Pb = h @ w1[64:128,:], h read from LDS.
// Accumulation order matches the round-3 kernels bit-exactly.
// ---------------------------------------------------------------------------
__global__ __launch_bounds__(256) void k_node(
    const float* __restrict__ x, const float* __restrict__ pw,
    const float* __restrict__ pbias, const float* __restrict__ w1,
    float* __restrict__ h, float* __restrict__ pa, float* __restrict__ pb) {
  __shared__ float hT[64][65];  // stride 65: conflict-free column reads
  const int lane = threadIdx.x & 63;   // node within tile
  const int q    = threadIdx.x >> 6;   // wave id = column quarter (uniform/wave)
  const int n    = blockIdx.x * 64 + lane;
  const int nc   = n < NN ? n : NN - 1;  // clamp for tail-block loads
  const bool valid = n < NN;

  // ---- phase 1: projection, 16 columns per thread ----
  float acc[16];
#pragma unroll
  for (int j = 0; j < 4; ++j) {
    float4 b = *(const float4*)(pbias + 16 * q + 4 * j);
    acc[4 * j + 0] = b.x; acc[4 * j + 1] = b.y;
    acc[4 * j + 2] = b.z; acc[4 * j + 3] = b.w;
  }
  const float4* xr = (const float4*)(x + (size_t)nc * IND);
#pragma unroll 4
  for (int kc = 0; kc < IND / 4; ++kc) {
    float4 xv = xr[kc];
    float xs[4] = {xv.x, xv.y, xv.z, xv.w};
#pragma unroll
    for (int kk = 0; kk < 4; ++kk) {
      const float4* wr = (const float4*)(pw + (size_t)(4 * kc + kk) * HD + 16 * q);
#pragma unroll
      for (int j = 0; j < 4; ++j) {
        float4 w = wr[j];
        acc[4 * j + 0] = fmaf(xs[kk], w.x, acc[4 * j + 0]);
        acc[4 * j + 1] = fmaf(xs[kk], w.y, acc[4 * j + 1]);
        acc[4 * j + 2] = fmaf(xs[kk], w.z, acc[4 * j + 2]);
        acc[4 * j + 3] = fmaf(xs[kk], w.w, acc[4 * j + 3]);
      }
    }
  }
  float4* hrow = (float4*)(h + (size_t)n * HD + 16 * q);
#pragma unroll
  for (int j = 0; j < 4; ++j) {
    float t0 = tanhf(acc[4 * j + 0]), t1 = tanhf(acc[4 * j + 1]);
    float t2 = tanhf(acc[4 * j + 2]), t3 = tanhf(acc[4 * j + 3]);
    if (valid) hrow[j] = make_float4(t0, t1, t2, t3);
    hT[lane][16 * q + 4 * j + 0] = t0;
    hT[lane][16 * q + 4 * j + 1] = t1;
    hT[lane][16 * q + 4 * j + 2] = t2;
    hT[lane][16 * q + 4 * j + 3] = t3;
  }
  __syncthreads();

  // ---- phase 2: Pa / Pb, 16 columns each per thread ----
  float accA[16], accB[16];
#pragma unroll
  for (int j = 0; j < 16; ++j) { accA[j] = 0.f; accB[j] = 0.f; }
#pragma unroll 4
  for (int k = 0; k < HD; ++k) {
    float z = hT[lane][k];
    const float4* wa = (const float4*)(w1 + (size_t)k * HD + 16 * q);
    const float4* wb = (const float4*)(w1 + (size_t)(HD + k) * HD + 16 * q);
#pragma unroll
    for (int j = 0; j < 4; ++j) {
      float4 a = wa[j]; float4 b = wb[j];
      accA[4 * j + 0] = fmaf(z, a.x, accA[4 * j + 0]);
      accA[4 * j + 1] = fmaf(z, a.y, accA[4 * j + 1]);
      accA[4 * j + 2] = fmaf(z, a.z, accA[4 * j + 2]);
      accA[4 * j + 3] = fmaf(z, a.w, accA[4 * j + 3]);
      accB[4 * j + 0] = fmaf(z, b.x, accB[4 * j + 0]);
      accB[4 * j + 1] = fmaf(z, b.y, accB[4 * j + 1]);
      accB[4 * j + 2] = fmaf(z, b.z, accB[4 * j + 2]);
      accB[4 * j + 3] = fmaf(z, b.w, accB[4 * j + 3]);
    }
  }
  if (valid) {
    float4* par = (float4*)(pa + (size_t)n * HD + 16 * q);
    float4* pbr = (float4*)(pb + (size_t)n * HD + 16 * q);
#pragma unroll
    for (int j = 0; j < 4; ++j) {
      par[j] = make_float4(accA[4 * j], accA[4 * j + 1], accA[4 * j + 2], accA[4 * j + 3]);
      pbr[j] = make_float4(accB[4 * j], accB[4 * j + 1], accB[4 * j + 2], accB[4 * j + 3]);
    }
  }
}

// ---------------------------------------------------------------------------
// Per-edge fused MLP + evidential head. One edge per thread.
//   hidden = relu(Pa[u] + Pb[v] + |z_u-z_v| @ Wc + (z_u*z_v) @ Wd + b1)
// Fully unrolled c-loop + VGPR cap 128 (4 waves/SIMD) so the compiler hoists
// the 16 float4 gather loads for memory-level parallelism.
// ---------------------------------------------------------------------------
__global__ __launch_bounds__(256, 4) void k_edge(
    const int* __restrict__ eu, const int* __restrict__ evi,
    const float* __restrict__ h, const float* __restrict__ pa,
    const float* __restrict__ pb, const float* __restrict__ w1,
    const float* __restrict__ b1, const float* __restrict__ w2,
    const float* __restrict__ b2, float* __restrict__ out) {
  int e = blockIdx.x * 256 + threadIdx.x;
  if (e >= NE) return;
  int u = eu[e], v = evi[e];

  const float* pau = pa + (size_t)u * HD;
  const float* pbv = pb + (size_t)v * HD;
  float acc[HD];
#pragma unroll
  for (int i = 0; i < HD / 4; ++i) {
    float4 A = *(const float4*)(pau + 4 * i);
    float4 B = *(const float4*)(pbv + 4 * i);
    float4 bb = *(const float4*)(b1 + 4 * i);
    acc[4 * i + 0] = A.x + B.x + bb.x;
    acc[4 * i + 1] = A.y + B.y + bb.y;
    acc[4 * i + 2] = A.z + B.z + bb.z;
    acc[4 * i + 3] = A.w + B.w + bb.w;
  }

  const float* hu = h + (size_t)u * HD;
  const float* hv = h + (size_t)v * HD;
#pragma unroll
  for (int c = 0; c < 4; ++c) {
    float cu[16], cv[16];
#pragma unroll
    for (int t = 0; t < 4; ++t) {
      *(float4*)&cu[4 * t] = *(const float4*)(hu + 16 * c + 4 * t);
      *(float4*)&cv[4 * t] = *(const float4*)(hv + 16 * c + 4 * t);
    }
#pragma unroll
    for (int j = 0; j < 16; ++j) {
      float zu = cu[j], zv = cv[j];
      float a = fabsf(zu - zv);
      float m = zu * zv;
      const float4* wc = (const float4*)(w1 + (size_t)(2 * HD + 16 * c + j) * HD);
      const float4* wd = (const float4*)(w1 + (size_t)(3 * HD + 16 * c + j) * HD);
#pragma unroll
      for (int i = 0; i < HD / 4; ++i) {
        float4 C = wc[i]; float4 D = wd[i];
        acc[4 * i + 0] = fmaf(a, C.x, fmaf(m, D.x, acc[4 * i + 0]));
        acc[4 * i + 1] = fmaf(a, C.y, fmaf(m, D.y, acc[4 * i + 1]));
        acc[4 * i + 2] = fmaf(a, C.z, fmaf(m, D.z, acc[4 * i + 2]));
        acc[4 * i + 3] = fmaf(a, C.w, fmaf(m, D.w, acc[4 * i + 3]));
      }
    }
  }

  // layer 2: [64] -> [2]; w2 wave-uniform scalar loads
  float l0 = b2[0], l1 = b2[1];
#pragma unroll
  for (int i = 0; i < HD; ++i) {
    float r = fmaxf(acc[i], 0.f);
    l0 = fmaf(r, w2[2 * i + 0], l0);
    l1 = fmaf(r, w2[2 * i + 1], l1);
  }

  // softplus = max(x,0) + log1p(exp(-|x|))  (matches jax.nn.softplus)
  float ev0 = fmaxf(l0, 0.f) + log1pf(expf(-fabsf(l0)));
  float ev1 = fmaxf(l1, 0.f) + log1pf(expf(-fabsf(l1)));
  float a0 = ev0 + 1.f, a1 = ev1 + 1.f;
  float S = a0 + a1;
  float unc = 2.f / (S + 1e-12f);
  float p0 = a0 / S, p1 = a1 / S;

  // outputs flat: evidence[E,2] | alpha[E,2] | uncertainty[E] | probs[E,2]
  ((float2*)out)[e] = make_float2(ev0, ev1);
  ((float2*)(out + 2 * (size_t)NE))[e] = make_float2(a0, a1);
  (out + 4 * (size_t)NE)[e] = unc;
  ((float2*)(out + 5 * (size_t)NE))[e] = make_float2(p0, p1);
}

// ---------------------------------------------------------------------------
extern "C" void kernel_launch(void* const* d_in, const int* in_sizes, int n_in,
                              void* d_out, int out_size, void* d_ws, size_t ws_size,
                              hipStream_t stream) {
  const int* ei      = (const int*)d_in[0];    // [2, E]
  const float* x     = (const float*)d_in[1];  // [NN, 256]
  const float* pw    = (const float*)d_in[2];  // [256, 64]
  const float* pbias = (const float*)d_in[3];  // [64]
  const float* w1    = (const float*)d_in[4];  // [256, 64]
  const float* b1    = (const float*)d_in[5];  // [64]
  const float* w2    = (const float*)d_in[6];  // [64, 2]
  const float* b2    = (const float*)d_in[7];  // [2]
  float* out = (float*)d_out;

  // ws layout: h [NN,64] | Pa [NN,64] | Pb [NN,64]  = 38.4 MB total
  float* h  = (float*)d_ws;
  float* pa = h + (size_t)NN * HD;
  float* pb = pa + (size_t)NN * HD;

  k_node<<<(NN + 63) / 64, 256, 0, stream>>>(x, pw, pbias, w1, h, pa, pb);
  k_edge<<<(NE + 255) / 256, 256, 0, stream>>>(ei, ei + NE, h, pa, pb,
                                               w1, b1, w2, b2, out);
}

// Round 15
// 507.105 us; speedup vs baseline: 1.0689x; 1.0689x over previous
//
#include <hip/hip_runtime.h>
#include <math.h>

#define NN 50000
#define NE 800000
#define IND 256
#define HD 64
#define RECH 192  // halves per node record: h[64] | Pa[64] | Pb[64] = 384 B

typedef __attribute__((ext_vector_type(8))) _Float16 half8;

// ---------------------------------------------------------------------------
// Fused node kernel. Block = 256 threads = 4 waves, covers 64 nodes.
// Wave q computes output columns [16q,16q+16). Phase 1: h = tanh(x@pw+b),
// kept fp32 in LDS for phase 2, stored fp16 into rec. Phase 2: Pa/Pb from
// LDS h (fp32 math, bit-identical accumulation order), stored fp16 into rec.
// ---------------------------------------------------------------------------
__global__ __launch_bounds__(256) void k_node(
    const float* __restrict__ x, const float* __restrict__ pw,
    const float* __restrict__ pbias, const float* __restrict__ w1,
    _Float16* __restrict__ rec) {
  __shared__ float hT[64][65];
  const int lane = threadIdx.x & 63;
  const int q    = threadIdx.x >> 6;
  const int n    = blockIdx.x * 64 + lane;
  const int nc   = n < NN ? n : NN - 1;
  const bool valid = n < NN;

  // ---- phase 1: projection, 16 columns per thread ----
  float acc[16];
#pragma unroll
  for (int j = 0; j < 4; ++j) {
    float4 b = *(const float4*)(pbias + 16 * q + 4 * j);
    acc[4 * j + 0] = b.x; acc[4 * j + 1] = b.y;
    acc[4 * j + 2] = b.z; acc[4 * j + 3] = b.w;
  }
  const float4* xr = (const float4*)(x + (size_t)nc * IND);
#pragma unroll 4
  for (int kc = 0; kc < IND / 4; ++kc) {
    float4 xv = xr[kc];
    float xs[4] = {xv.x, xv.y, xv.z, xv.w};
#pragma unroll
    for (int kk = 0; kk < 4; ++kk) {
      const float4* wr = (const float4*)(pw + (size_t)(4 * kc + kk) * HD + 16 * q);
#pragma unroll
      for (int j = 0; j < 4; ++j) {
        float4 w = wr[j];
        acc[4 * j + 0] = fmaf(xs[kk], w.x, acc[4 * j + 0]);
        acc[4 * j + 1] = fmaf(xs[kk], w.y, acc[4 * j + 1]);
        acc[4 * j + 2] = fmaf(xs[kk], w.z, acc[4 * j + 2]);
        acc[4 * j + 3] = fmaf(xs[kk], w.w, acc[4 * j + 3]);
      }
    }
  }
  float t[16];
#pragma unroll
  for (int j = 0; j < 16; ++j) t[j] = tanhf(acc[j]);
#pragma unroll
  for (int j = 0; j < 16; ++j) hT[lane][16 * q + j] = t[j];
  if (valid) {
    half8 w0, w1h;
#pragma unroll
    for (int k = 0; k < 8; ++k) { w0[k] = (_Float16)t[k]; w1h[k] = (_Float16)t[8 + k]; }
    _Float16* hrec = rec + (size_t)n * RECH + 16 * q;
    *(half8*)(hrec + 0) = w0;
    *(half8*)(hrec + 8) = w1h;
  }
  __syncthreads();

  // ---- phase 2: Pa / Pb, 16 columns each per thread ----
  float accA[16], accB[16];
#pragma unroll
  for (int j = 0; j < 16; ++j) { accA[j] = 0.f; accB[j] = 0.f; }
#pragma unroll 4
  for (int k = 0; k < HD; ++k) {
    float z = hT[lane][k];
    const float4* wa = (const float4*)(w1 + (size_t)k * HD + 16 * q);
    const float4* wb = (const float4*)(w1 + (size_t)(HD + k) * HD + 16 * q);
#pragma unroll
    for (int j = 0; j < 4; ++j) {
      float4 a = wa[j]; float4 b = wb[j];
      accA[4 * j + 0] = fmaf(z, a.x, accA[4 * j + 0]);
      accA[4 * j + 1] = fmaf(z, a.y, accA[4 * j + 1]);
      accA[4 * j + 2] = fmaf(z, a.z, accA[4 * j + 2]);
      accA[4 * j + 3] = fmaf(z, a.w, accA[4 * j + 3]);
      accB[4 * j + 0] = fmaf(z, b.x, accB[4 * j + 0]);
      accB[4 * j + 1] = fmaf(z, b.y, accB[4 * j + 1]);
      accB[4 * j + 2] = fmaf(z, b.z, accB[4 * j + 2]);
      accB[4 * j + 3] = fmaf(z, b.w, accB[4 * j + 3]);
    }
  }
  if (valid) {
    half8 a0, a1, b0, b1v;
#pragma unroll
    for (int k = 0; k < 8; ++k) {
      a0[k] = (_Float16)accA[k]; a1[k] = (_Float16)accA[8 + k];
      b0[k] = (_Float16)accB[k]; b1v[k] = (_Float16)accB[8 + k];
    }
    _Float16* parec = rec + (size_t)n * RECH + 64 + 16 * q;
    _Float16* pbrec = rec + (size_t)n * RECH + 128 + 16 * q;
    *(half8*)(parec + 0) = a0; *(half8*)(parec + 8) = a1;
    *(half8*)(pbrec + 0) = b0; *(half8*)(pbrec + 8) = b1v;
  }
}

// ---------------------------------------------------------------------------
// Per-edge fused MLP + evidential head. One edge per thread.
// Gathers two fp16 records (u,v): 512 B/edge over 2 address streams
// (was 1 KB over 4). fp32 accumulate; unchanged accumulation order.
// ---------------------------------------------------------------------------
__global__ __launch_bounds__(256, 4) void k_edge(
    const int* __restrict__ eu, const int* __restrict__ evi,
    const _Float16* __restrict__ rec, const float* __restrict__ w1,
    const float* __restrict__ b1, const float* __restrict__ w2,
    const float* __restrict__ b2, float* __restrict__ out) {
  int e = blockIdx.x * 256 + threadIdx.x;
  if (e >= NE) return;
  int u = eu[e], v = evi[e];

  const _Float16* ru = rec + (size_t)u * RECH;
  const _Float16* rv = rec + (size_t)v * RECH;

  float acc[HD];
#pragma unroll
  for (int i8 = 0; i8 < 8; ++i8) {
    half8 pa8 = *(const half8*)(ru + 64 + 8 * i8);   // Pa[u]
    half8 pb8 = *(const half8*)(rv + 128 + 8 * i8);  // Pb[v]
    float4 bb0 = *(const float4*)(b1 + 8 * i8);
    float4 bb1 = *(const float4*)(b1 + 8 * i8 + 4);
    acc[8 * i8 + 0] = (float)pa8[0] + (float)pb8[0] + bb0.x;
    acc[8 * i8 + 1] = (float)pa8[1] + (float)pb8[1] + bb0.y;
    acc[8 * i8 + 2] = (float)pa8[2] + (float)pb8[2] + bb0.z;
    acc[8 * i8 + 3] = (float)pa8[3] + (float)pb8[3] + bb0.w;
    acc[8 * i8 + 4] = (float)pa8[4] + (float)pb8[4] + bb1.x;
    acc[8 * i8 + 5] = (float)pa8[5] + (float)pb8[5] + bb1.y;
    acc[8 * i8 + 6] = (float)pa8[6] + (float)pb8[6] + bb1.z;
    acc[8 * i8 + 7] = (float)pa8[7] + (float)pb8[7] + bb1.w;
  }

#pragma unroll
  for (int c = 0; c < 4; ++c) {
    half8 u0 = *(const half8*)(ru + 16 * c);
    half8 u1 = *(const half8*)(ru + 16 * c + 8);
    half8 v0 = *(const half8*)(rv + 16 * c);
    half8 v1 = *(const half8*)(rv + 16 * c + 8);
    float cu[16], cv[16];
#pragma unroll
    for (int k = 0; k < 8; ++k) {
      cu[k] = (float)u0[k]; cu[8 + k] = (float)u1[k];
      cv[k] = (float)v0[k]; cv[8 + k] = (float)v1[k];
    }
#pragma unroll
    for (int j = 0; j < 16; ++j) {
      float zu = cu[j], zv = cv[j];
      float a = fabsf(zu - zv);
      float m = zu * zv;
      const float4* wc = (const float4*)(w1 + (size_t)(2 * HD + 16 * c + j) * HD);
      const float4* wd = (const float4*)(w1 + (size_t)(3 * HD + 16 * c + j) * HD);
#pragma unroll
      for (int i = 0; i < HD / 4; ++i) {
        float4 C = wc[i]; float4 D = wd[i];
        acc[4 * i + 0] = fmaf(a, C.x, fmaf(m, D.x, acc[4 * i + 0]));
        acc[4 * i + 1] = fmaf(a, C.y, fmaf(m, D.y, acc[4 * i + 1]));
        acc[4 * i + 2] = fmaf(a, C.z, fmaf(m, D.z, acc[4 * i + 2]));
        acc[4 * i + 3] = fmaf(a, C.w, fmaf(m, D.w, acc[4 * i + 3]));
      }
    }
  }

  // layer 2: [64] -> [2]
  float l0 = b2[0], l1 = b2[1];
#pragma unroll
  for (int i = 0; i < HD; ++i) {
    float r = fmaxf(acc[i], 0.f);
    l0 = fmaf(r, w2[2 * i + 0], l0);
    l1 = fmaf(r, w2[2 * i + 1], l1);
  }

  // softplus = max(x,0) + log1p(exp(-|x|))
  float ev0 = fmaxf(l0, 0.f) + log1pf(expf(-fabsf(l0)));
  float ev1 = fmaxf(l1, 0.f) + log1pf(expf(-fabsf(l1)));
  float a0 = ev0 + 1.f, a1 = ev1 + 1.f;
  float S = a0 + a1;
  float unc = 2.f / (S + 1e-12f);
  float p0 = a0 / S, p1 = a1 / S;

  // outputs flat: evidence[E,2] | alpha[E,2] | uncertainty[E] | probs[E,2]
  ((float2*)out)[e] = make_float2(ev0, ev1);
  ((float2*)(out + 2 * (size_t)NE))[e] = make_float2(a0, a1);
  (out + 4 * (size_t)NE)[e] = unc;
  ((float2*)(out + 5 * (size_t)NE))[e] = make_float2(p0, p1);
}

// ---------------------------------------------------------------------------
extern "C" void kernel_launch(void* const* d_in, const int* in_sizes, int n_in,
                              void* d_out, int out_size, void* d_ws, size_t ws_size,
                              hipStream_t stream) {
  const int* ei      = (const int*)d_in[0];    // [2, E]
  const float* x     = (const float*)d_in[1];  // [NN, 256]
  const float* pw    = (const float*)d_in[2];  // [256, 64]
  const float* pbias = (const float*)d_in[3];  // [64]
  const float* w1    = (const float*)d_in[4];  // [256, 64]
  const float* b1    = (const float*)d_in[5];  // [64]
  const float* w2    = (const float*)d_in[6];  // [64, 2]
  const float* b2    = (const float*)d_in[7];  // [2]
  float* out = (float*)d_out;

  // ws: packed fp16 node records [NN][192] = 19.2 MB
  _Float16* rec = (_Float16*)d_ws;

  k_node<<<(NN + 63) / 64, 256, 0, stream>>>(x, pw, pbias, w1, rec);
  k_edge<<<(NE + 255) / 256, 256, 0, stream>>>(ei, ei + NE, rec,
                                               w1, b1, w2, b2, out);
}

// Round 16
// 355.675 us; speedup vs baseline: 1.5240x; 1.4258x over previous
//
#include <hip/hip_runtime.h>
#include <math.h>

#define NN 50000
#define NE 800000
#define IND 256
#define HD 64
#define RECH 192  // halves per node record: h[64] | Pa[64] | Pb[64] = 384 B

typedef __attribute__((ext_vector_type(8))) _Float16 half8;

// ---------------------------------------------------------------------------
// Fused node kernel. Block = 256 threads = 4 waves, covers 64 nodes.
// Wave q computes output columns [16q,16q+16). qu = readfirstlane(q) makes
// all weight/bias pointer bases provably wave-uniform -> s_load (scalar
// cache), not per-lane VMEM broadcast loads. Math order unchanged.
// ---------------------------------------------------------------------------
__global__ __launch_bounds__(256) void k_node(
    const float* __restrict__ x, const float* __restrict__ pw,
    const float* __restrict__ pbias, const float* __restrict__ w1,
    _Float16* __restrict__ rec) {
  __shared__ float hT[64][65];
  const int lane = threadIdx.x & 63;
  const int q    = threadIdx.x >> 6;
  const int qu   = __builtin_amdgcn_readfirstlane(q);  // wave-uniform column quarter
  const int n    = blockIdx.x * 64 + lane;
  const int nc   = n < NN ? n : NN - 1;
  const bool valid = n < NN;

  // ---- phase 1: projection, 16 columns per thread ----
  float acc[16];
#pragma unroll
  for (int j = 0; j < 4; ++j) {
    float4 b = *(const float4*)(pbias + 16 * qu + 4 * j);
    acc[4 * j + 0] = b.x; acc[4 * j + 1] = b.y;
    acc[4 * j + 2] = b.z; acc[4 * j + 3] = b.w;
  }
  const float4* xr = (const float4*)(x + (size_t)nc * IND);
#pragma unroll 4
  for (int kc = 0; kc < IND / 4; ++kc) {
    float4 xv = xr[kc];
    float xs[4] = {xv.x, xv.y, xv.z, xv.w};
#pragma unroll
    for (int kk = 0; kk < 4; ++kk) {
      const float4* wr = (const float4*)(pw + (size_t)(4 * kc + kk) * HD + 16 * qu);
#pragma unroll
      for (int j = 0; j < 4; ++j) {
        float4 w = wr[j];
        acc[4 * j + 0] = fmaf(xs[kk], w.x, acc[4 * j + 0]);
        acc[4 * j + 1] = fmaf(xs[kk], w.y, acc[4 * j + 1]);
        acc[4 * j + 2] = fmaf(xs[kk], w.z, acc[4 * j + 2]);
        acc[4 * j + 3] = fmaf(xs[kk], w.w, acc[4 * j + 3]);
      }
    }
  }
  float t[16];
#pragma unroll
  for (int j = 0; j < 16; ++j) t[j] = tanhf(acc[j]);
#pragma unroll
  for (int j = 0; j < 16; ++j) hT[lane][16 * q + j] = t[j];
  if (valid) {
    half8 w0, w1h;
#pragma unroll
    for (int k = 0; k < 8; ++k) { w0[k] = (_Float16)t[k]; w1h[k] = (_Float16)t[8 + k]; }
    _Float16* hrec = rec + (size_t)n * RECH + 16 * q;
    *(half8*)(hrec + 0) = w0;
    *(half8*)(hrec + 8) = w1h;
  }
  __syncthreads();

  // ---- phase 2: Pa / Pb, 16 columns each per thread ----
  float accA[16], accB[16];
#pragma unroll
  for (int j = 0; j < 16; ++j) { accA[j] = 0.f; accB[j] = 0.f; }
#pragma unroll 4
  for (int k = 0; k < HD; ++k) {
    float z = hT[lane][k];
    const float4* wa = (const float4*)(w1 + (size_t)k * HD + 16 * qu);
    const float4* wb = (const float4*)(w1 + (size_t)(HD + k) * HD + 16 * qu);
#pragma unroll
    for (int j = 0; j < 4; ++j) {
      float4 a = wa[j]; float4 b = wb[j];
      accA[4 * j + 0] = fmaf(z, a.x, accA[4 * j + 0]);
      accA[4 * j + 1] = fmaf(z, a.y, accA[4 * j + 1]);
      accA[4 * j + 2] = fmaf(z, a.z, accA[4 * j + 2]);
      accA[4 * j + 3] = fmaf(z, a.w, accA[4 * j + 3]);
      accB[4 * j + 0] = fmaf(z, b.x, accB[4 * j + 0]);
      accB[4 * j + 1] = fmaf(z, b.y, accB[4 * j + 1]);
      accB[4 * j + 2] = fmaf(z, b.z, accB[4 * j + 2]);
      accB[4 * j + 3] = fmaf(z, b.w, accB[4 * j + 3]);
    }
  }
  if (valid) {
    half8 a0, a1, b0, b1v;
#pragma unroll
    for (int k = 0; k < 8; ++k) {
      a0[k] = (_Float16)accA[k]; a1[k] = (_Float16)accA[8 + k];
      b0[k] = (_Float16)accB[k]; b1v[k] = (_Float16)accB[8 + k];
    }
    _Float16* parec = rec + (size_t)n * RECH + 64 + 16 * q;
    _Float16* pbrec = rec + (size_t)n * RECH + 128 + 16 * q;
    *(half8*)(parec + 0) = a0; *(half8*)(parec + 8) = a1;
    *(half8*)(pbrec + 0) = b0; *(half8*)(pbrec + 8) = b1v;
  }
}

// ---------------------------------------------------------------------------
// Per-edge fused MLP + evidential head. One edge per thread.
// BYTE-IDENTICAL to the round-15 passing version (233 µs @ 14% HBM).
// ---------------------------------------------------------------------------
__global__ __launch_bounds__(256, 4) void k_edge(
    const int* __restrict__ eu, const int* __restrict__ evi,
    const _Float16* __restrict__ rec, const float* __restrict__ w1,
    const float* __restrict__ b1, const float* __restrict__ w2,
    const float* __restrict__ b2, float* __restrict__ out) {
  int e = blockIdx.x * 256 + threadIdx.x;
  if (e >= NE) return;
  int u = eu[e], v = evi[e];

  const _Float16* ru = rec + (size_t)u * RECH;
  const _Float16* rv = rec + (size_t)v * RECH;

  float acc[HD];
#pragma unroll
  for (int i8 = 0; i8 < 8; ++i8) {
    half8 pa8 = *(const half8*)(ru + 64 + 8 * i8);   // Pa[u]
    half8 pb8 = *(const half8*)(rv + 128 + 8 * i8);  // Pb[v]
    float4 bb0 = *(const float4*)(b1 + 8 * i8);
    float4 bb1 = *(const float4*)(b1 + 8 * i8 + 4);
    acc[8 * i8 + 0] = (float)pa8[0] + (float)pb8[0] + bb0.x;
    acc[8 * i8 + 1] = (float)pa8[1] + (float)pb8[1] + bb0.y;
    acc[8 * i8 + 2] = (float)pa8[2] + (float)pb8[2] + bb0.z;
    acc[8 * i8 + 3] = (float)pa8[3] + (float)pb8[3] + bb0.w;
    acc[8 * i8 + 4] = (float)pa8[4] + (float)pb8[4] + bb1.x;
    acc[8 * i8 + 5] = (float)pa8[5] + (float)pb8[5] + bb1.y;
    acc[8 * i8 + 6] = (float)pa8[6] + (float)pb8[6] + bb1.z;
    acc[8 * i8 + 7] = (float)pa8[7] + (float)pb8[7] + bb1.w;
  }

#pragma unroll
  for (int c = 0; c < 4; ++c) {
    half8 u0 = *(const half8*)(ru + 16 * c);
    half8 u1 = *(const half8*)(ru + 16 * c + 8);
    half8 v0 = *(const half8*)(rv + 16 * c);
    half8 v1 = *(const half8*)(rv + 16 * c + 8);
    float cu[16], cv[16];
#pragma unroll
    for (int k = 0; k < 8; ++k) {
      cu[k] = (float)u0[k]; cu[8 + k] = (float)u1[k];
      cv[k] = (float)v0[k]; cv[8 + k] = (float)v1[k];
    }
#pragma unroll
    for (int j = 0; j < 16; ++j) {
      float zu = cu[j], zv = cv[j];
      float a = fabsf(zu - zv);
      float m = zu * zv;
      const float4* wc = (const float4*)(w1 + (size_t)(2 * HD + 16 * c + j) * HD);
      const float4* wd = (const float4*)(w1 + (size_t)(3 * HD + 16 * c + j) * HD);
#pragma unroll
      for (int i = 0; i < HD / 4; ++i) {
        float4 C = wc[i]; float4 D = wd[i];
        acc[4 * i + 0] = fmaf(a, C.x, fmaf(m, D.x, acc[4 * i + 0]));
        acc[4 * i + 1] = fmaf(a, C.y, fmaf(m, D.y, acc[4 * i + 1]));
        acc[4 * i + 2] = fmaf(a, C.z, fmaf(m, D.z, acc[4 * i + 2]));
        acc[4 * i + 3] = fmaf(a, C.w, fmaf(m, D.w, acc[4 * i + 3]));
      }
    }
  }

  // layer 2: [64] -> [2]
  float l0 = b2[0], l1 = b2[1];
#pragma unroll
  for (int i = 0; i < HD; ++i) {
    float r = fmaxf(acc[i], 0.f);
    l0 = fmaf(r, w2[2 * i + 0], l0);
    l1 = fmaf(r, w2[2 * i + 1], l1);
  }

  // softplus = max(x,0) + log1p(exp(-|x|))
  float ev0 = fmaxf(l0, 0.f) + log1pf(expf(-fabsf(l0)));
  float ev1 = fmaxf(l1, 0.f) + log1pf(expf(-fabsf(l1)));
  float a0 = ev0 + 1.f, a1 = ev1 + 1.f;
  float S = a0 + a1;
  float unc = 2.f / (S + 1e-12f);
  float p0 = a0 / S, p1 = a1 / S;

  // outputs flat: evidence[E,2] | alpha[E,2] | uncertainty[E] | probs[E,2]
  ((float2*)out)[e] = make_float2(ev0, ev1);
  ((float2*)(out + 2 * (size_t)NE))[e] = make_float2(a0, a1);
  (out + 4 * (size_t)NE)[e] = unc;
  ((float2*)(out + 5 * (size_t)NE))[e] = make_float2(p0, p1);
}

// ---------------------------------------------------------------------------
extern "C" void kernel_launch(void* const* d_in, const int* in_sizes, int n_in,
                              void* d_out, int out_size, void* d_ws, size_t ws_size,
                              hipStream_t stream) {
  const int* ei      = (const int*)d_in[0];    // [2, E]
  const float* x     = (const float*)d_in[1];  // [NN, 256]
  const float* pw    = (const float*)d_in[2];  // [256, 64]
  const float* pbias = (const float*)d_in[3];  // [64]
  const float* w1    = (const float*)d_in[4];  // [256, 64]
  const float* b1    = (const float*)d_in[5];  // [64]
  const float* w2    = (const float*)d_in[6];  // [64, 2]
  const float* b2    = (const float*)d_in[7];  // [2]
  float* out = (float*)d_out;

  // ws: packed fp16 node records [NN][192] = 19.2 MB
  _Float16* rec = (_Float16*)d_ws;

  k_node<<<(NN + 63) / 64, 256, 0, stream>>>(x, pw, pbias, w1, rec);
  k_edge<<<(NE + 255) / 256, 256, 0, stream>>>(ei, ei + NE, rec,
                                               w1, b1, w2, b2, out);
}

// Round 17
// 332.788 us; speedup vs baseline: 1.6288x; 1.0688x over previous
//
#include <hip/hip_runtime.h>
#include <math.h>

#define NN 50000
#define NE 800000
#define IND 256
#define HD 64

typedef _Float16 half8 __attribute__((ext_vector_type(8)));
typedef float f32x4 __attribute__((ext_vector_type(4)));

// ---------------------------------------------------------------------------
// k_prep: wt[64][256] fp16 = transpose of w1[256][64]. 16384 threads.
// ---------------------------------------------------------------------------
__global__ __launch_bounds__(256) void k_prep(const float* __restrict__ w1,
                                              _Float16* __restrict__ wt) {
  int t = blockIdx.x * 256 + threadIdx.x;  // t = n*256 + k
  int n = t >> 8, k = t & 255;
  wt[t] = (_Float16)w1[k * HD + n];
}

// ---------------------------------------------------------------------------
// k_node: h = tanh(x @ pw + pbias), stored fp16 [NN][64].
// 4 waves / 64 nodes per block; wave q does columns [16q,16q+16).
// qu = readfirstlane(q): weight pointers wave-uniform -> s_load (round-16 win).
// ---------------------------------------------------------------------------
__global__ __launch_bounds__(256) void k_node(
    const float* __restrict__ x, const float* __restrict__ pw,
    const float* __restrict__ pbias, _Float16* __restrict__ h) {
  const int lane = threadIdx.x & 63;
  const int q    = threadIdx.x >> 6;
  const int qu   = __builtin_amdgcn_readfirstlane(q);
  const int n    = blockIdx.x * 64 + lane;
  const int nc   = n < NN ? n : NN - 1;
  const bool valid = n < NN;

  float acc[16];
#pragma unroll
  for (int j = 0; j < 4; ++j) {
    float4 b = *(const float4*)(pbias + 16 * qu + 4 * j);
    acc[4 * j + 0] = b.x; acc[4 * j + 1] = b.y;
    acc[4 * j + 2] = b.z; acc[4 * j + 3] = b.w;
  }
  const float4* xr = (const float4*)(x + (size_t)nc * IND);
#pragma unroll 4
  for (int kc = 0; kc < IND / 4; ++kc) {
    float4 xv = xr[kc];
    float xs[4] = {xv.x, xv.y, xv.z, xv.w};
#pragma unroll
    for (int kk = 0; kk < 4; ++kk) {
      const float4* wr = (const float4*)(pw + (size_t)(4 * kc + kk) * HD + 16 * qu);
#pragma unroll
      for (int j = 0; j < 4; ++j) {
        float4 w = wr[j];
        acc[4 * j + 0] = fmaf(xs[kk], w.x, acc[4 * j + 0]);
        acc[4 * j + 1] = fmaf(xs[kk], w.y, acc[4 * j + 1]);
        acc[4 * j + 2] = fmaf(xs[kk], w.z, acc[4 * j + 2]);
        acc[4 * j + 3] = fmaf(xs[kk], w.w, acc[4 * j + 3]);
      }
    }
  }
  if (valid) {
    half8 w0, w1h;
#pragma unroll
    for (int k = 0; k < 8; ++k) {
      w0[k]  = (_Float16)tanhf(acc[k]);
      w1h[k] = (_Float16)tanhf(acc[8 + k]);
    }
    _Float16* hrec = h + (size_t)n * HD + 16 * q;
    *(half8*)(hrec + 0) = w0;
    *(half8*)(hrec + 8) = w1h;
  }
}

// ---------------------------------------------------------------------------
// k_edge: MFMA edge MLP. 1 wave = 16 edges (M=16), K=256 feat, N=64 hidden.
// feat = [z_u | z_v | |z_u-z_v| | z_u*z_v] built in-register from two 256-B
// h-row gathers. 32x mfma_f32_16x16x32_f16 per wave. Layer 2 via shfl_xor.
// A-frag: row=lane&15 (edge), k=(lane>>4)*8+j. B-frag from wt[n][k] (contig k).
// C/D: col(lane&15)=hidden n, row((lane>>4)*4+reg)=edge  [m89-verified].
// ---------------------------------------------------------------------------
__global__ __launch_bounds__(256) void k_edge(
    const int* __restrict__ eu, const int* __restrict__ evi,
    const _Float16* __restrict__ h, const _Float16* __restrict__ wt,
    const float* __restrict__ b1, const float* __restrict__ w2,
    const float* __restrict__ b2, float* __restrict__ out) {
  const int lane = threadIdx.x & 63;
  const int wid  = threadIdx.x >> 6;
  const int r = lane & 15;            // edge row within tile / hidden col
  const int g = lane >> 4;            // k-group
  const int e0 = (blockIdx.x * 4 + wid) * 16;   // NE = 12500*64 exactly

  const int u = eu[e0 + r];
  const int v = evi[e0 + r];
  const _Float16* hu = h + (size_t)u * HD;
  const _Float16* hv = h + (size_t)v * HD;
  half8 hu0 = *(const half8*)(hu + 8 * g);
  half8 hu1 = *(const half8*)(hu + 8 * g + 32);
  half8 hv0 = *(const half8*)(hv + 8 * g);
  half8 hv1 = *(const half8*)(hv + 8 * g + 32);

  half8 ad0 = hu0 - hv0, ad1 = hu1 - hv1;
#pragma unroll
  for (int k = 0; k < 8; ++k) {
    ad0[k] = ad0[k] < (_Float16)0.f ? (_Float16)(-ad0[k]) : ad0[k];
    ad1[k] = ad1[k] < (_Float16)0.f ? (_Float16)(-ad1[k]) : ad1[k];
  }
  half8 pr0 = hu0 * hv0, pr1 = hu1 * hv1;

  // A fragments per k-step s: feature blocks in reference order
  half8 af[8] = {hu0, hu1, hv0, hv1, ad0, ad1, pr0, pr1};

  f32x4 acc[4] = {{0.f,0.f,0.f,0.f},{0.f,0.f,0.f,0.f},
                  {0.f,0.f,0.f,0.f},{0.f,0.f,0.f,0.f}};
#pragma unroll
  for (int nt = 0; nt < 4; ++nt) {
    const _Float16* wr = wt + (size_t)(16 * nt + r) * 256 + 8 * g;
#pragma unroll
    for (int s = 0; s < 8; ++s) {
      half8 bf = *(const half8*)(wr + 32 * s);
      acc[nt] = __builtin_amdgcn_mfma_f32_16x16x32_f16(af[s], bf, acc[nt], 0, 0, 0);
    }
  }

  // layer 2 partials: lane holds hidden[edge=4g+j][n=16nt+r]
  float p0[4] = {0.f, 0.f, 0.f, 0.f}, p1[4] = {0.f, 0.f, 0.f, 0.f};
#pragma unroll
  for (int nt = 0; nt < 4; ++nt) {
    const int n = 16 * nt + r;
    const float bb = b1[n];
    const float w20 = w2[2 * n], w21 = w2[2 * n + 1];
#pragma unroll
    for (int j = 0; j < 4; ++j) {
      float hval = fmaxf(acc[nt][j] + bb, 0.f);
      p0[j] = fmaf(hval, w20, p0[j]);
      p1[j] = fmaf(hval, w21, p1[j]);
    }
  }
  // butterfly reduce across the 16 r-lanes (n dimension)
#pragma unroll
  for (int m = 1; m <= 8; m <<= 1) {
#pragma unroll
    for (int j = 0; j < 4; ++j) {
      p0[j] += __shfl_xor(p0[j], m);
      p1[j] += __shfl_xor(p1[j], m);
    }
  }

  if (r < 4) {  // lane r finishes edge 4g + r (static-index select, rule #20)
    float s0 = r == 0 ? p0[0] : r == 1 ? p0[1] : r == 2 ? p0[2] : p0[3];
    float s1 = r == 0 ? p1[0] : r == 1 ? p1[1] : r == 2 ? p1[2] : p1[3];
    float l0 = s0 + b2[0];
    float l1 = s1 + b2[1];
    // softplus = max(x,0) + log1p(exp(-|x|))
    float ev0 = fmaxf(l0, 0.f) + log1pf(expf(-fabsf(l0)));
    float ev1 = fmaxf(l1, 0.f) + log1pf(expf(-fabsf(l1)));
    float a0 = ev0 + 1.f, a1 = ev1 + 1.f;
    float S = a0 + a1;
    float unc = 2.f / (S + 1e-12f);
    float q0 = a0 / S, q1 = a1 / S;

    const size_t E = (size_t)e0 + 4 * g + r;
    *(float2*)(out + 2 * E)                   = make_float2(ev0, ev1);
    *(float2*)(out + 2 * (size_t)NE + 2 * E)  = make_float2(a0, a1);
    out[4 * (size_t)NE + E]                   = unc;
    *(float2*)(out + 5 * (size_t)NE + 2 * E)  = make_float2(q0, q1);
  }
}

// ---------------------------------------------------------------------------
extern "C" void kernel_launch(void* const* d_in, const int* in_sizes, int n_in,
                              void* d_out, int out_size, void* d_ws, size_t ws_size,
                              hipStream_t stream) {
  const int* ei      = (const int*)d_in[0];    // [2, E]
  const float* x     = (const float*)d_in[1];  // [NN, 256]
  const float* pw    = (const float*)d_in[2];  // [256, 64]
  const float* pbias = (const float*)d_in[3];  // [64]
  const float* w1    = (const float*)d_in[4];  // [256, 64]
  const float* b1    = (const float*)d_in[5];  // [64]
  const float* w2    = (const float*)d_in[6];  // [64, 2]
  const float* b2    = (const float*)d_in[7];  // [2]
  float* out = (float*)d_out;

  // ws: wt [64][256] fp16 (32 KB) | h [NN][64] fp16 (6.4 MB)
  _Float16* wt = (_Float16*)d_ws;
  _Float16* h  = wt + 64 * 256;

  k_prep<<<64, 256, 0, stream>>>(w1, wt);
  k_node<<<(NN + 63) / 64, 256, 0, stream>>>(x, pw, pbias, h);
  k_edge<<<NE / 64, 256, 0, stream>>>(ei, ei + NE, h, wt, b1, w2, b2, out);
}